// Round 1
// baseline (3582.970 us; speedup 1.0000x reference)
//
#include <hip/hip_runtime.h>
#include <math.h>

#define N_NODES 20000
#define N_EDGES 320000
#define HD 128
#define RD 50
#define RDP 52   // RD padded to multiple of 4 for float4 broadcast
#define NL 6
#define CUTV 5.0f
#define PI_F 3.14159265358979323846f
#define EBL 8    // edges per wave batch (edge kernels)
#define NB 4     // nodes per wave batch (node gemm kernels)

__device__ __forceinline__ float cutoff_f(float d) {
  float c = 0.5f * (cosf(d * (PI_F / CUTV)) + 1.0f);
  return d < CUTV ? c : 0.0f;
}
__device__ __forceinline__ float silu_f(float x) {
  return x / (1.0f + expf(-x));
}
__device__ __forceinline__ void wave_sync_lds() {
  asm volatile("s_waitcnt lgkmcnt(0)" ::: "memory");
  __builtin_amdgcn_wave_barrier();
}

// ---------------- CSR build ----------------
__global__ void k_hist(const int* __restrict__ ei, int* __restrict__ deg) {
  int e = blockIdx.x * blockDim.x + threadIdx.x;
  if (e < N_EDGES) atomicAdd(&deg[ei[N_EDGES + e]], 1);
}

__global__ void k_scan(const int* __restrict__ deg, int* __restrict__ rowptr,
                       int* __restrict__ cursor) {
  __shared__ int s[1024];
  __shared__ int run;
  int t = threadIdx.x;
  if (t == 0) run = 0;
  __syncthreads();
  for (int base = 0; base < N_NODES; base += 1024) {
    int idx = base + t;
    int v = (idx < N_NODES) ? deg[idx] : 0;
    s[t] = v;
    __syncthreads();
    for (int off = 1; off < 1024; off <<= 1) {
      int add = (t >= off) ? s[t - off] : 0;
      __syncthreads();
      s[t] += add;
      __syncthreads();
    }
    int excl = s[t] - v;
    int r = run;
    if (idx < N_NODES) { rowptr[idx] = r + excl; cursor[idx] = r + excl; }
    __syncthreads();
    if (t == 0) run += s[1023];
    __syncthreads();
  }
  if (t == 0) rowptr[N_NODES] = run;
}

__global__ void k_scatter(const int* __restrict__ ei, int* __restrict__ cursor,
                          int* __restrict__ eids) {
  int e = blockIdx.x * blockDim.x + threadIdx.x;
  if (e < N_EDGES) {
    int i = ei[N_EDGES + e];
    int p = atomicAdd(&cursor[i], 1);
    eids[p] = e;
  }
}

// ---------------- x0 = emb[z] ----------------
__global__ void k_init(const int* __restrict__ z, const float* __restrict__ emb,
                       float* __restrict__ x) {
  int idx = blockIdx.x * blockDim.x + threadIdx.x;
  if (idx < N_NODES * 32) {
    int n = idx >> 5, c4 = idx & 31;
    float4 v = ((const float4*)emb)[z[n] * 32 + c4];
    ((float4*)x)[n * 32 + c4] = v;
  }
}

// ---------------- first edge block: agg = segsum(x[j] * Wn) ----------------
__global__ __launch_bounds__(512)
void k_edge_dp(const int* __restrict__ ei, const float* __restrict__ ew,
               const float* __restrict__ means, const float* __restrict__ betas,
               const float* __restrict__ dp_w, const float* __restrict__ dp_b,
               const float* __restrict__ x0,
               const int* __restrict__ rowptr, const int* __restrict__ eids,
               float* __restrict__ agg) {
  __shared__ __align__(16) float s_w[RDP * HD];
  __shared__ float s_mb[2 * RD];
  __shared__ float s_b[HD];
  __shared__ __align__(16) float s_attr[8][EBL][RDP];
  int t = threadIdx.x;
  for (int k = t; k < RDP * HD; k += 512) s_w[k] = (k < RD * HD) ? dp_w[k] : 0.0f;
  if (t < RD) s_mb[t] = means[t];
  if (t >= 64 && t < 64 + RD) s_mb[RD + t - 64] = betas[t - 64];
  if (t >= 128 && t < 256) s_b[t - 128] = dp_b[t - 128];
  __syncthreads();
  int wv = t >> 6, lane = t & 63;
  int gw = blockIdx.x * 8 + wv, nw = gridDim.x * 8;
  for (int n = gw; n < N_NODES; n += nw) {
    float acc0 = 0.f, acc1 = 0.f;
    int beg = rowptr[n], end = rowptr[n + 1];
    for (int ie = beg; ie < end; ie += EBL) {
      int nb = end - ie; nb = nb < EBL ? nb : EBL;
      float Cc[EBL]; int jj[EBL];
      #pragma unroll
      for (int b = 0; b < EBL; ++b) {
        float Cb = 0.f; int jb = 0;
        if (b < nb) {
          int e = eids[ie + b];
          float d = ew[e];
          jb = ei[e];
          Cb = cutoff_f(d);
          float ex = expf(-d);
          if (lane < RD) {
            float em = ex - s_mb[lane];
            s_attr[wv][b][lane] = Cb * expf(-s_mb[RD + lane] * em * em);
          } else if (lane < RDP) s_attr[wv][b][lane] = 0.f;
        } else {
          if (lane < RDP) s_attr[wv][b][lane] = 0.f;
        }
        Cc[b] = Cb; jj[b] = jb;
      }
      wave_sync_lds();
      float t0[EBL], t1[EBL];
      #pragma unroll
      for (int b = 0; b < EBL; ++b) { t0[b] = 0.f; t1[b] = 0.f; }
      for (int k4 = 0; k4 < RDP; k4 += 4) {
        float4 av[EBL];
        #pragma unroll
        for (int b = 0; b < EBL; ++b) av[b] = *(const float4*)&s_attr[wv][b][k4];
        #pragma unroll
        for (int kk = 0; kk < 4; ++kk) {
          float w0 = s_w[(k4 + kk) * HD + lane];
          float w1v = s_w[(k4 + kk) * HD + 64 + lane];
          #pragma unroll
          for (int b = 0; b < EBL; ++b) {
            float a = ((const float*)&av[b])[kk];
            t0[b] += a * w0; t1[b] += a * w1v;
          }
        }
      }
      #pragma unroll
      for (int b = 0; b < EBL; ++b) {
        float W0 = (t0[b] + s_b[lane]) * Cc[b];
        float W1 = (t1[b] + s_b[64 + lane]) * Cc[b];
        const float* xr = x0 + (size_t)jj[b] * HD;
        acc0 += xr[lane] * W0;
        acc1 += xr[64 + lane] * W1;
      }
      __builtin_amdgcn_wave_barrier();
    }
    agg[n * HD + lane] = acc0;
    agg[n * HD + 64 + lane] = acc1;
  }
}

// ---------------- per-layer fused edge kernel ----------------
__global__ __launch_bounds__(512)
void k_edge_layer(const int* __restrict__ ei, const float* __restrict__ ew,
                  const float* __restrict__ means, const float* __restrict__ betas,
                  const float* __restrict__ w1, const float* __restrict__ b1,
                  const float* __restrict__ w2, const float* __restrict__ b2,
                  const float* __restrict__ h,
                  const int* __restrict__ rowptr, const int* __restrict__ eids,
                  float* __restrict__ hagg) {
  __shared__ __align__(16) float s_w1[RDP * HD];
  __shared__ __align__(16) float s_w2[HD * HD];
  __shared__ float s_b1[HD], s_b2[HD];
  __shared__ float s_mb[2 * RD];
  __shared__ __align__(16) float s_attr[8][EBL][RDP];
  __shared__ __align__(16) float s_t[8][EBL][HD];
  int t = threadIdx.x;
  for (int k = t; k < RDP * HD; k += 512) s_w1[k] = (k < RD * HD) ? w1[k] : 0.0f;
  for (int k = t; k < HD * HD; k += 512) s_w2[k] = w2[k];
  if (t < HD) s_b1[t] = b1[t];
  if (t >= 128 && t < 256) s_b2[t - 128] = b2[t - 128];
  if (t >= 256 && t < 256 + RD) s_mb[t - 256] = means[t - 256];
  if (t >= 320 && t < 320 + RD) s_mb[RD + t - 320] = betas[t - 320];
  __syncthreads();
  int wv = t >> 6, lane = t & 63;
  int gw = blockIdx.x * 8 + wv, nw = gridDim.x * 8;
  for (int n = gw; n < N_NODES; n += nw) {
    float acc0 = 0.f, acc1 = 0.f;
    int beg = rowptr[n], end = rowptr[n + 1];
    for (int ie = beg; ie < end; ie += EBL) {
      int nb = end - ie; nb = nb < EBL ? nb : EBL;
      float Cc[EBL]; int jj[EBL];
      #pragma unroll
      for (int b = 0; b < EBL; ++b) {
        float Cb = 0.f; int jb = 0;
        if (b < nb) {
          int e = eids[ie + b];
          float d = ew[e];
          jb = ei[e];
          Cb = cutoff_f(d);
          float ex = expf(-d);
          if (lane < RD) {
            float em = ex - s_mb[lane];
            s_attr[wv][b][lane] = Cb * expf(-s_mb[RD + lane] * em * em);
          } else if (lane < RDP) s_attr[wv][b][lane] = 0.f;
        } else {
          if (lane < RDP) s_attr[wv][b][lane] = 0.f;
        }
        Cc[b] = Cb; jj[b] = jb;
      }
      wave_sync_lds();
      float t0[EBL], t1[EBL];
      #pragma unroll
      for (int b = 0; b < EBL; ++b) { t0[b] = 0.f; t1[b] = 0.f; }
      // t = attr @ w1
      for (int k4 = 0; k4 < RDP; k4 += 4) {
        float4 av[EBL];
        #pragma unroll
        for (int b = 0; b < EBL; ++b) av[b] = *(const float4*)&s_attr[wv][b][k4];
        #pragma unroll
        for (int kk = 0; kk < 4; ++kk) {
          float w0 = s_w1[(k4 + kk) * HD + lane];
          float w1v = s_w1[(k4 + kk) * HD + 64 + lane];
          #pragma unroll
          for (int b = 0; b < EBL; ++b) {
            float a = ((const float*)&av[b])[kk];
            t0[b] += a * w0; t1[b] += a * w1v;
          }
        }
      }
      // silu, stage t to LDS, reuse t0/t1 as y accumulators
      #pragma unroll
      for (int b = 0; b < EBL; ++b) {
        float u0 = silu_f(t0[b] + s_b1[lane]);
        float u1 = silu_f(t1[b] + s_b1[64 + lane]);
        s_t[wv][b][lane] = u0;
        s_t[wv][b][64 + lane] = u1;
        t0[b] = 0.f; t1[b] = 0.f;
      }
      wave_sync_lds();
      // y = silu(t) @ w2
      for (int k4 = 0; k4 < HD; k4 += 4) {
        float4 av[EBL];
        #pragma unroll
        for (int b = 0; b < EBL; ++b) av[b] = *(const float4*)&s_t[wv][b][k4];
        #pragma unroll
        for (int kk = 0; kk < 4; ++kk) {
          float w0 = s_w2[(k4 + kk) * HD + lane];
          float w1v = s_w2[(k4 + kk) * HD + 64 + lane];
          #pragma unroll
          for (int b = 0; b < EBL; ++b) {
            float a = ((const float*)&av[b])[kk];
            t0[b] += a * w0; t1[b] += a * w1v;
          }
        }
      }
      #pragma unroll
      for (int b = 0; b < EBL; ++b) {
        float W0 = (t0[b] + s_b2[lane]) * Cc[b];
        float W1 = (t1[b] + s_b2[64 + lane]) * Cc[b];
        const float* hr = h + (size_t)jj[b] * HD;
        acc0 += hr[lane] * W0;
        acc1 += hr[64 + lane] * W1;
      }
      __builtin_amdgcn_wave_barrier();
    }
    float inv = (end > beg) ? 1.0f / (float)(end - beg) : 0.0f;
    hagg[n * HD + lane] = acc0 * inv;
    hagg[n * HD + 64 + lane] = acc1 * inv;
  }
}

// ---------------- generic node GEMM: out = [silu](in1[,in2] @ W + bias) [+ out] ----------------
template <int K, bool HASB, bool SILU, bool ADD, int NWAVE>
__global__ __launch_bounds__(NWAVE * 64)
void k_ngemm(const float* __restrict__ in1, const float* __restrict__ in2,
             const float* __restrict__ W, const float* __restrict__ bias,
             float* __restrict__ out) {
  __shared__ __align__(16) float s_W[K * HD];
  __shared__ __align__(16) float s_row[NWAVE][NB][K];
  int t = threadIdx.x;
  for (int k = t; k < K * HD; k += NWAVE * 64) s_W[k] = W[k];
  __syncthreads();
  int wv = t >> 6, lane = t & 63;
  int gw = blockIdx.x * NWAVE + wv, nw = gridDim.x * NWAVE;
  for (int n0 = gw * NB; n0 < N_NODES; n0 += nw * NB) {
    int nb = N_NODES - n0; nb = nb < NB ? nb : NB;
    for (int b = 0; b < nb; ++b) {
      int n = n0 + b;
      s_row[wv][b][lane] = in1[(size_t)n * HD + lane];
      s_row[wv][b][64 + lane] = in1[(size_t)n * HD + 64 + lane];
      if constexpr (K == 256) {
        s_row[wv][b][128 + lane] = in2[(size_t)n * HD + lane];
        s_row[wv][b][192 + lane] = in2[(size_t)n * HD + 64 + lane];
      }
    }
    wave_sync_lds();
    float a0[NB], a1[NB];
    #pragma unroll
    for (int b = 0; b < NB; ++b) { a0[b] = 0.f; a1[b] = 0.f; }
    for (int k4 = 0; k4 < K; k4 += 4) {
      float4 av[NB];
      #pragma unroll
      for (int b = 0; b < NB; ++b) av[b] = *(const float4*)&s_row[wv][b][k4];
      #pragma unroll
      for (int kk = 0; kk < 4; ++kk) {
        float w0 = s_W[(k4 + kk) * HD + lane];
        float w1v = s_W[(k4 + kk) * HD + 64 + lane];
        #pragma unroll
        for (int b = 0; b < NB; ++b) {
          float a = ((const float*)&av[b])[kk];
          a0[b] += a * w0; a1[b] += a * w1v;
        }
      }
    }
    __builtin_amdgcn_wave_barrier();
    for (int b = 0; b < nb; ++b) {
      int n = n0 + b;
      float v0 = a0[b], v1 = a1[b];
      if constexpr (HASB) { v0 += bias[lane]; v1 += bias[64 + lane]; }
      if constexpr (SILU) { v0 = silu_f(v0); v1 = silu_f(v1); }
      if constexpr (ADD) {
        out[(size_t)n * HD + lane] += v0;
        out[(size_t)n * HD + 64 + lane] += v1;
      } else {
        out[(size_t)n * HD + lane] = v0;
        out[(size_t)n * HD + 64 + lane] = v1;
      }
    }
  }
}

extern "C" void kernel_launch(void* const* d_in, const int* in_sizes, int n_in,
                              void* d_out, int out_size, void* d_ws, size_t ws_size,
                              hipStream_t stream) {
  const int* z = (const int*)d_in[0];
  const int* ei = (const int*)d_in[1];
  const float* ew = (const float*)d_in[2];
  const float* emb = (const float*)d_in[3];
  const float* means = (const float*)d_in[4];
  const float* betas = (const float*)d_in[5];
  const float* dp_w = (const float*)d_in[6];
  const float* dp_b = (const float*)d_in[7];
  const float* comb_w = (const float*)d_in[8];
  const float* comb_b = (const float*)d_in[9];
  const float* mlp_w1 = (const float*)d_in[10];
  const float* mlp_b1 = (const float*)d_in[11];
  const float* mlp_w2 = (const float*)d_in[12];
  const float* mlp_b2 = (const float*)d_in[13];
  const float* lin1_w = (const float*)d_in[14];
  const float* lin2_w = (const float*)d_in[15];
  const float* lin2_b = (const float*)d_in[16];
  const float* lin_w = (const float*)d_in[17];
  const float* lin_b = (const float*)d_in[18];
  float* x = (float*)d_out;

  int* rowptr = (int*)d_ws;             // N+1 (padded to 20032)
  int* deg = rowptr + 20032;            // N
  int* cursor = deg + 20032;            // N
  int* eids = cursor + 20032;           // E
  float* hbuf = (float*)(eids + N_EDGES);
  float* aggb = hbuf + (size_t)N_NODES * HD;
  float* h2b = aggb + (size_t)N_NODES * HD;

  hipMemsetAsync(deg, 0, N_NODES * sizeof(int), stream);
  k_hist<<<(N_EDGES + 255) / 256, 256, 0, stream>>>(ei, deg);
  k_scan<<<1, 1024, 0, stream>>>(deg, rowptr, cursor);
  k_scatter<<<(N_EDGES + 255) / 256, 256, 0, stream>>>(ei, cursor, eids);
  k_init<<<(N_NODES * 32 + 255) / 256, 256, 0, stream>>>(z, emb, x);
  k_edge_dp<<<512, 512, 0, stream>>>(ei, ew, means, betas, dp_w, dp_b, x,
                                     rowptr, eids, aggb);
  k_ngemm<256, true, false, false, 4><<<1250, 256, 0, stream>>>(x, aggb, comb_w, comb_b, x);
  for (int l = 0; l < NL; ++l) {
    k_ngemm<128, false, false, false, 8><<<625, 512, 0, stream>>>(
        x, nullptr, lin1_w + (size_t)l * HD * HD, nullptr, hbuf);
    k_edge_layer<<<512, 512, 0, stream>>>(
        ei, ew, means, betas,
        mlp_w1 + (size_t)l * RD * HD, mlp_b1 + (size_t)l * HD,
        mlp_w2 + (size_t)l * HD * HD, mlp_b2 + (size_t)l * HD,
        hbuf, rowptr, eids, aggb);
    k_ngemm<128, true, true, false, 8><<<625, 512, 0, stream>>>(
        aggb, nullptr, lin2_w + (size_t)l * HD * HD, lin2_b + (size_t)l * HD, h2b);
    k_ngemm<128, true, false, true, 8><<<625, 512, 0, stream>>>(
        h2b, nullptr, lin_w + (size_t)l * HD * HD, lin_b + (size_t)l * HD, x);
  }
}

// Round 2
// 1380.222 us; speedup vs baseline: 2.5959x; 2.5959x over previous
//
#include <hip/hip_runtime.h>
#include <math.h>

#define N_NODES 20000
#define N_EDGES 320000
#define NTILES  5000   // N_EDGES / 64
#define HD 128
#define RD 50
#define NL 6
#define CUTV 5.0f
#define PI_F 3.14159265358979323846f
#define NB 4

typedef __attribute__((ext_vector_type(8))) short short8;
typedef __attribute__((ext_vector_type(4))) float f32x4;

__device__ __forceinline__ float cutoff_f(float d) {
  float c = 0.5f * (__cosf(d * (PI_F / CUTV)) + 1.0f);
  return d < CUTV ? c : 0.0f;
}
__device__ __forceinline__ float silu_f(float x) {
  return x / (1.0f + __expf(-x));
}
__device__ __forceinline__ unsigned short bf16bits(float f) {
  union { float f; unsigned int u; } v; v.f = f;
  unsigned int r = v.u + 0x7fffu + ((v.u >> 16) & 1u);
  return (unsigned short)(r >> 16);
}
__device__ __forceinline__ float bfu_hi(unsigned int bits_in_high) {
  union { unsigned int u; float f; } v; v.u = bits_in_high; return v.f;
}
__device__ __forceinline__ f32x4 mfma16(short8 a, short8 b, f32x4 c) {
  return __builtin_amdgcn_mfma_f32_16x16x32_bf16(a, b, c, 0, 0, 0);
}
__device__ __forceinline__ void wave_sync_lds() {
  asm volatile("s_waitcnt lgkmcnt(0)" ::: "memory");
  __builtin_amdgcn_wave_barrier();
}

// ---------------- CSR build ----------------
__global__ void k_hist(const int* __restrict__ ei, int* __restrict__ deg) {
  int e = blockIdx.x * blockDim.x + threadIdx.x;
  if (e < N_EDGES) atomicAdd(&deg[ei[N_EDGES + e]], 1);
}

__global__ void k_scan(const int* __restrict__ deg, int* __restrict__ rowptr,
                       int* __restrict__ cursor) {
  __shared__ int s[1024];
  __shared__ int run;
  int t = threadIdx.x;
  if (t == 0) run = 0;
  __syncthreads();
  for (int base = 0; base < N_NODES; base += 1024) {
    int idx = base + t;
    int v = (idx < N_NODES) ? deg[idx] : 0;
    s[t] = v;
    __syncthreads();
    for (int off = 1; off < 1024; off <<= 1) {
      int add = (t >= off) ? s[t - off] : 0;
      __syncthreads();
      s[t] += add;
      __syncthreads();
    }
    int excl = s[t] - v;
    int r = run;
    if (idx < N_NODES) { rowptr[idx] = r + excl; cursor[idx] = r + excl; }
    __syncthreads();
    if (t == 0) run += s[1023];
    __syncthreads();
  }
  if (t == 0) rowptr[N_NODES] = run;
}

__global__ void k_scatter(const int* __restrict__ ei, int* __restrict__ cursor,
                          int* __restrict__ eids) {
  int e = blockIdx.x * blockDim.x + threadIdx.x;
  if (e < N_EDGES) {
    int i = ei[N_EDGES + e];
    int p = atomicAdd(&cursor[i], 1);
    eids[p] = e;
  }
}

// ---------------- x0 = emb[z] ----------------
__global__ void k_init(const int* __restrict__ z, const float* __restrict__ emb,
                       float* __restrict__ x) {
  int idx = blockIdx.x * blockDim.x + threadIdx.x;
  if (idx < N_NODES * 32) {
    int n = idx >> 5, c4 = idx & 31;
    float4 v = ((const float4*)emb)[z[n] * 32 + c4];
    ((float4*)x)[n * 32 + c4] = v;
  }
}

// ---------------- attr precompute (sorted order, A-fragment layout) --------
// attr_fr[tile][kgrp(8)][e(64)][i(8)] bf16; includes cutoff factor.
// Also C_sorted[p], src_sorted[p].
__global__ __launch_bounds__(256)
void k_attr(const int* __restrict__ ei, const float* __restrict__ ew,
            const int* __restrict__ eids,
            const float* __restrict__ means, const float* __restrict__ betas,
            unsigned short* __restrict__ attr_fr, float* __restrict__ Csrt,
            int* __restrict__ srcj) {
  int gid = blockIdx.x * blockDim.x + threadIdx.x;   // 0 .. NTILES*512
  int tile = gid >> 9, s = gid & 511;
  int kg = s >> 6, e = s & 63;
  int p = tile * 64 + e;
  int eo = eids[p];
  float d = ew[eo];
  float C = cutoff_f(d);
  float ex = __expf(-d);
  short8 out;
  #pragma unroll
  for (int i = 0; i < 8; ++i) {
    int k = kg * 8 + i;
    float v = 0.0f;
    if (k < RD) {
      float em = ex - means[k];
      v = C * __expf(-betas[k] * em * em);
    }
    out[i] = (short)bf16bits(v);
  }
  *(short8*)(attr_fr + (size_t)gid * 8) = out;
  if (kg == 0) {
    Csrt[p] = C;
    srcj[p] = ei[eo];
  }
}

// ---------------- Pass A: per-edge filter via MFMA ----------------
// TWO=true : W = (silu(attr@w1 + b1) @ w2 + bF) * C
// TWO=false: W = (attr@w1 + bF) * C
// 256 threads = 4 waves; 64-edge tiles; wave w owns ntiles {2w, 2w+1}.
template <bool TWO>
__global__ __launch_bounds__(256, 2)
void k_filter(const unsigned short* __restrict__ afr_g,
              const float* __restrict__ Csrt,
              const float* __restrict__ w1g, const float* __restrict__ b1g,
              const float* __restrict__ w2g, const float* __restrict__ bFg,
              unsigned short* __restrict__ Wout) {
  __shared__ unsigned short s_u[8192];   // u frags (16KB) / W-tile staging [64][128]
  int t = threadIdx.x;
  int wv = t >> 6, lane = t & 63;
  int c = lane & 15, g = lane >> 4;

  // persistent B fragments (registers, built from global once per block)
  short8 B1[2][2];
  #pragma unroll
  for (int ntl = 0; ntl < 2; ++ntl) {
    int col = (2 * wv + ntl) * 16 + c;
    #pragma unroll
    for (int kt = 0; kt < 2; ++kt) {
      short8 v;
      #pragma unroll
      for (int i = 0; i < 8; ++i) {
        int k = 32 * kt + 8 * g + i;
        v[i] = (k < RD) ? (short)bf16bits(w1g[k * HD + col]) : (short)0;
      }
      B1[ntl][kt] = v;
    }
  }
  short8 B2[2][4];
  if (TWO) {
    #pragma unroll
    for (int ntl = 0; ntl < 2; ++ntl) {
      int col = (2 * wv + ntl) * 16 + c;
      #pragma unroll
      for (int kt = 0; kt < 4; ++kt) {
        short8 v;
        #pragma unroll
        for (int i = 0; i < 8; ++i) {
          int k = 32 * kt + 8 * g + i;
          v[i] = (short)bf16bits(w2g[k * HD + col]);
        }
        B2[ntl][kt] = v;
      }
    }
  }
  float b1v[2], bFv[2];
  #pragma unroll
  for (int ntl = 0; ntl < 2; ++ntl) {
    int col = (2 * wv + ntl) * 16 + c;
    b1v[ntl] = TWO ? b1g[col] : 0.0f;
    bFv[ntl] = bFg[col];
  }

  for (int tile = blockIdx.x; tile < NTILES; tile += gridDim.x) {
    const unsigned short* afr = afr_g + (size_t)tile * 4096;
    f32x4 acc[4][2];
    #pragma unroll
    for (int mt = 0; mt < 4; ++mt) {
      acc[mt][0] = (f32x4){0.f, 0.f, 0.f, 0.f};
      acc[mt][1] = (f32x4){0.f, 0.f, 0.f, 0.f};
    }
    // GEMM1: t = attr @ w1   (M=64 edges, N=128, K=64 padded)
    #pragma unroll
    for (int kt = 0; kt < 2; ++kt) {
      #pragma unroll
      for (int mt = 0; mt < 4; ++mt) {
        short8 a = *(const short8*)(afr + ((size_t)((4 * kt + g) * 64 + (16 * mt + c))) * 8);
        acc[mt][0] = mfma16(a, B1[0][kt], acc[mt][0]);
        acc[mt][1] = mfma16(a, B1[1][kt], acc[mt][1]);
      }
    }
    if (TWO) {
      // silu + stage u as A-fragments [kgrp][e][i]
      #pragma unroll
      for (int mt = 0; mt < 4; ++mt) {
        #pragma unroll
        for (int ntl = 0; ntl < 2; ++ntl) {
          int ch = (2 * wv + ntl) * 16 + c;
          #pragma unroll
          for (int r = 0; r < 4; ++r) {
            int e = 16 * mt + 4 * g + r;
            float v = acc[mt][ntl][r] + b1v[ntl];
            v = silu_f(v);
            s_u[((ch >> 3) * 64 + e) * 8 + (ch & 7)] = bf16bits(v);
          }
        }
      }
      __syncthreads();
      #pragma unroll
      for (int mt = 0; mt < 4; ++mt) {
        acc[mt][0] = (f32x4){0.f, 0.f, 0.f, 0.f};
        acc[mt][1] = (f32x4){0.f, 0.f, 0.f, 0.f};
      }
      // GEMM2: y = u @ w2   (K=128)
      #pragma unroll
      for (int kt = 0; kt < 4; ++kt) {
        #pragma unroll
        for (int mt = 0; mt < 4; ++mt) {
          short8 a = *(const short8*)(s_u + ((4 * kt + g) * 64 + (16 * mt + c)) * 8);
          acc[mt][0] = mfma16(a, B2[0][kt], acc[mt][0]);
          acc[mt][1] = mfma16(a, B2[1][kt], acc[mt][1]);
        }
      }
      __syncthreads();
    }
    // epilogue: W = (acc + bF) * C -> s_u as [64][128] bf16
    #pragma unroll
    for (int mt = 0; mt < 4; ++mt) {
      float Cv[4];
      #pragma unroll
      for (int r = 0; r < 4; ++r) Cv[r] = Csrt[tile * 64 + 16 * mt + 4 * g + r];
      #pragma unroll
      for (int ntl = 0; ntl < 2; ++ntl) {
        int ch = (2 * wv + ntl) * 16 + c;
        #pragma unroll
        for (int r = 0; r < 4; ++r) {
          int e = 16 * mt + 4 * g + r;
          float v = (acc[mt][ntl][r] + bFv[ntl]) * Cv[r];
          s_u[e * 128 + ch] = bf16bits(v);
        }
      }
    }
    __syncthreads();
    // coalesced store of the 16KB W tile
    {
      short8* dst = (short8*)(Wout + (size_t)tile * 8192);
      const short8* srcv = (const short8*)s_u;
      #pragma unroll
      for (int k = 0; k < 4; ++k) dst[t + 256 * k] = srcv[t + 256 * k];
    }
    __syncthreads();
  }
}

// ---------------- Pass B: segment sum  out[n] = (sum_p h[srcj[p]]*W[p]) [*inv] --
template <bool INV>
__global__ __launch_bounds__(256)
void k_segsum(const unsigned short* __restrict__ Wst, const float* __restrict__ h,
              const int* __restrict__ rowptr, const int* __restrict__ srcj,
              float* __restrict__ out) {
  int t = threadIdx.x, wv = t >> 6, lane = t & 63;
  int gw = blockIdx.x * 4 + wv, nw = gridDim.x * 4;
  for (int n = gw; n < N_NODES; n += nw) {
    int beg = rowptr[n], end = rowptr[n + 1];
    float a0 = 0.f, a1 = 0.f;
    for (int p = beg; p < end; ++p) {
      int j = srcj[p];
      unsigned int wb = *(const unsigned int*)(Wst + (size_t)p * 128 + 2 * lane);
      float2 hv = *(const float2*)(h + (size_t)j * 128 + 2 * lane);
      a0 += hv.x * bfu_hi(wb << 16);
      a1 += hv.y * bfu_hi(wb & 0xffff0000u);
    }
    float inv = 1.0f;
    if (INV) inv = (end > beg) ? 1.0f / (float)(end - beg) : 0.0f;
    *(float2*)(out + (size_t)n * 128 + 2 * lane) = make_float2(a0 * inv, a1 * inv);
  }
}

// ---------------- generic node GEMM (unchanged from R1) ----------------
template <int K, bool HASB, bool SILU, bool ADD, int NWAVE>
__global__ __launch_bounds__(NWAVE * 64)
void k_ngemm(const float* __restrict__ in1, const float* __restrict__ in2,
             const float* __restrict__ W, const float* __restrict__ bias,
             float* __restrict__ out) {
  __shared__ __align__(16) float s_W[K * HD];
  __shared__ __align__(16) float s_row[NWAVE][NB][K];
  int t = threadIdx.x;
  for (int k = t; k < K * HD; k += NWAVE * 64) s_W[k] = W[k];
  __syncthreads();
  int wv = t >> 6, lane = t & 63;
  int gw = blockIdx.x * NWAVE + wv, nw = gridDim.x * NWAVE;
  for (int n0 = gw * NB; n0 < N_NODES; n0 += nw * NB) {
    int nb = N_NODES - n0; nb = nb < NB ? nb : NB;
    for (int b = 0; b < nb; ++b) {
      int n = n0 + b;
      s_row[wv][b][lane] = in1[(size_t)n * HD + lane];
      s_row[wv][b][64 + lane] = in1[(size_t)n * HD + 64 + lane];
      if constexpr (K == 256) {
        s_row[wv][b][128 + lane] = in2[(size_t)n * HD + lane];
        s_row[wv][b][192 + lane] = in2[(size_t)n * HD + 64 + lane];
      }
    }
    wave_sync_lds();
    float a0[NB], a1[NB];
    #pragma unroll
    for (int b = 0; b < NB; ++b) { a0[b] = 0.f; a1[b] = 0.f; }
    for (int k4 = 0; k4 < K; k4 += 4) {
      float4 av[NB];
      #pragma unroll
      for (int b = 0; b < NB; ++b) av[b] = *(const float4*)&s_row[wv][b][k4];
      #pragma unroll
      for (int kk = 0; kk < 4; ++kk) {
        float w0 = s_W[(k4 + kk) * HD + lane];
        float w1v = s_W[(k4 + kk) * HD + 64 + lane];
        #pragma unroll
        for (int b = 0; b < NB; ++b) {
          float a = ((const float*)&av[b])[kk];
          a0[b] += a * w0; a1[b] += a * w1v;
        }
      }
    }
    __builtin_amdgcn_wave_barrier();
    for (int b = 0; b < nb; ++b) {
      int n = n0 + b;
      float v0 = a0[b], v1 = a1[b];
      if constexpr (HASB) { v0 += bias[lane]; v1 += bias[64 + lane]; }
      if constexpr (SILU) { v0 = silu_f(v0); v1 = silu_f(v1); }
      if constexpr (ADD) {
        out[(size_t)n * HD + lane] += v0;
        out[(size_t)n * HD + 64 + lane] += v1;
      } else {
        out[(size_t)n * HD + lane] = v0;
        out[(size_t)n * HD + 64 + lane] = v1;
      }
    }
  }
}

extern "C" void kernel_launch(void* const* d_in, const int* in_sizes, int n_in,
                              void* d_out, int out_size, void* d_ws, size_t ws_size,
                              hipStream_t stream) {
  const int* z = (const int*)d_in[0];
  const int* ei = (const int*)d_in[1];
  const float* ew = (const float*)d_in[2];
  const float* emb = (const float*)d_in[3];
  const float* means = (const float*)d_in[4];
  const float* betas = (const float*)d_in[5];
  const float* dp_w = (const float*)d_in[6];
  const float* dp_b = (const float*)d_in[7];
  const float* comb_w = (const float*)d_in[8];
  const float* comb_b = (const float*)d_in[9];
  const float* mlp_w1 = (const float*)d_in[10];
  const float* mlp_b1 = (const float*)d_in[11];
  const float* mlp_w2 = (const float*)d_in[12];
  const float* mlp_b2 = (const float*)d_in[13];
  const float* lin1_w = (const float*)d_in[14];
  const float* lin2_w = (const float*)d_in[15];
  const float* lin2_b = (const float*)d_in[16];
  const float* lin_w = (const float*)d_in[17];
  const float* lin_b = (const float*)d_in[18];
  float* x = (float*)d_out;

  // workspace layout (all 16B aligned)
  int* rowptr = (int*)d_ws;                         // 20032
  int* deg = rowptr + 20032;                        // 20032
  int* cursor = deg + 20032;                        // 20032
  int* eids = cursor + 20032;                       // E
  int* srcj = eids + N_EDGES;                       // E
  float* Csrt = (float*)(srcj + N_EDGES);           // E
  unsigned short* attr_fr = (unsigned short*)(Csrt + N_EDGES);   // E*64 bf16
  unsigned short* Wst = attr_fr + (size_t)N_EDGES * 64;          // E*128 bf16
  float* hbuf = (float*)(Wst + (size_t)N_EDGES * 128);
  float* aggb = hbuf + (size_t)N_NODES * HD;
  float* h2b = aggb + (size_t)N_NODES * HD;

  hipMemsetAsync(deg, 0, N_NODES * sizeof(int), stream);
  k_hist<<<(N_EDGES + 255) / 256, 256, 0, stream>>>(ei, deg);
  k_scan<<<1, 1024, 0, stream>>>(deg, rowptr, cursor);
  k_scatter<<<(N_EDGES + 255) / 256, 256, 0, stream>>>(ei, cursor, eids);
  k_attr<<<NTILES * 2, 256, 0, stream>>>(ei, ew, eids, means, betas,
                                         attr_fr, Csrt, srcj);
  k_init<<<(N_NODES * 32 + 255) / 256, 256, 0, stream>>>(z, emb, x);

  // dp block: W = (attr@dp_w + dp_b)*C ; agg = segsum(x[j]*W)
  k_filter<false><<<1250, 256, 0, stream>>>(attr_fr, Csrt, dp_w, nullptr,
                                            nullptr, dp_b, Wst);
  k_segsum<false><<<1024, 256, 0, stream>>>(Wst, x, rowptr, srcj, aggb);
  k_ngemm<256, true, false, false, 4><<<1250, 256, 0, stream>>>(x, aggb, comb_w, comb_b, x);

  for (int l = 0; l < NL; ++l) {
    k_ngemm<128, false, false, false, 8><<<625, 512, 0, stream>>>(
        x, nullptr, lin1_w + (size_t)l * HD * HD, nullptr, hbuf);
    k_filter<true><<<1250, 256, 0, stream>>>(
        attr_fr, Csrt,
        mlp_w1 + (size_t)l * RD * HD, mlp_b1 + (size_t)l * HD,
        mlp_w2 + (size_t)l * HD * HD, mlp_b2 + (size_t)l * HD, Wst);
    k_segsum<true><<<1024, 256, 0, stream>>>(Wst, hbuf, rowptr, srcj, aggb);
    k_ngemm<128, true, true, false, 8><<<625, 512, 0, stream>>>(
        aggb, nullptr, lin2_w + (size_t)l * HD * HD, lin2_b + (size_t)l * HD, h2b);
    k_ngemm<128, true, false, true, 8><<<625, 512, 0, stream>>>(
        h2b, nullptr, lin_w + (size_t)l * HD * HD, lin_b + (size_t)l * HD, x);
  }
}

// Round 3
// 1148.813 us; speedup vs baseline: 3.1188x; 1.2014x over previous
//
#include <hip/hip_runtime.h>
#include <math.h>

#define N_NODES 20000
#define N_EDGES 320000
#define NTILES  5000   // N_EDGES / 64
#define NROWT   313    // ceil(N_NODES/64)
#define HD 128
#define RD 50
#define NL 6
#define CUTV 5.0f
#define PI_F 3.14159265358979323846f

typedef __attribute__((ext_vector_type(8))) short short8;
typedef __attribute__((ext_vector_type(4))) float f32x4;

__device__ __forceinline__ float cutoff_f(float d) {
  float c = 0.5f * (__cosf(d * (PI_F / CUTV)) + 1.0f);
  return d < CUTV ? c : 0.0f;
}
__device__ __forceinline__ float silu_f(float x) {
  return x / (1.0f + __expf(-x));
}
__device__ __forceinline__ unsigned short bf16bits(float f) {
  union { float f; unsigned int u; } v; v.f = f;
  unsigned int r = v.u + 0x7fffu + ((v.u >> 16) & 1u);
  return (unsigned short)(r >> 16);
}
__device__ __forceinline__ float bfu_hi(unsigned int bits_in_high) {
  union { unsigned int u; float f; } v; v.u = bits_in_high; return v.f;
}
__device__ __forceinline__ f32x4 mfma16(short8 a, short8 b, f32x4 c) {
  return __builtin_amdgcn_mfma_f32_16x16x32_bf16(a, b, c, 0, 0, 0);
}
__device__ __forceinline__ void wave_sync_lds() {
  asm volatile("s_waitcnt lgkmcnt(0)" ::: "memory");
  __builtin_amdgcn_wave_barrier();
}
// split 8 consecutive floats into hi/lo bf16 fragments
__device__ __forceinline__ void split8(const float* __restrict__ p,
                                       short8& h, short8& l) {
  float4 v0 = *(const float4*)p;
  float4 v1 = *(const float4*)(p + 4);
  float vv[8] = {v0.x, v0.y, v0.z, v0.w, v1.x, v1.y, v1.z, v1.w};
  #pragma unroll
  for (int i = 0; i < 8; ++i) {
    unsigned short hb = bf16bits(vv[i]);
    h[i] = (short)hb;
    l[i] = (short)bf16bits(vv[i] - bfu_hi((unsigned int)hb << 16));
  }
}

// ---------------- CSR build ----------------
__global__ void k_hist(const int* __restrict__ ei, int* __restrict__ deg) {
  int e = blockIdx.x * blockDim.x + threadIdx.x;
  if (e < N_EDGES) atomicAdd(&deg[ei[N_EDGES + e]], 1);
}

__global__ void k_scan(const int* __restrict__ deg, int* __restrict__ rowptr,
                       int* __restrict__ cursor) {
  __shared__ int s[1024];
  __shared__ int run;
  int t = threadIdx.x;
  if (t == 0) run = 0;
  __syncthreads();
  for (int base = 0; base < N_NODES; base += 1024) {
    int idx = base + t;
    int v = (idx < N_NODES) ? deg[idx] : 0;
    s[t] = v;
    __syncthreads();
    for (int off = 1; off < 1024; off <<= 1) {
      int add = (t >= off) ? s[t - off] : 0;
      __syncthreads();
      s[t] += add;
      __syncthreads();
    }
    int excl = s[t] - v;
    int r = run;
    if (idx < N_NODES) { rowptr[idx] = r + excl; cursor[idx] = r + excl; }
    __syncthreads();
    if (t == 0) run += s[1023];
    __syncthreads();
  }
  if (t == 0) rowptr[N_NODES] = run;
}

__global__ void k_scatter(const int* __restrict__ ei, int* __restrict__ cursor,
                          int* __restrict__ eids) {
  int e = blockIdx.x * blockDim.x + threadIdx.x;
  if (e < N_EDGES) {
    int i = ei[N_EDGES + e];
    int p = atomicAdd(&cursor[i], 1);
    eids[p] = e;
  }
}

// ---------------- x0 = emb[z] ----------------
__global__ void k_init(const int* __restrict__ z, const float* __restrict__ emb,
                       float* __restrict__ x) {
  int idx = blockIdx.x * blockDim.x + threadIdx.x;
  if (idx < N_NODES * 32) {
    int n = idx >> 5, c4 = idx & 31;
    float4 v = ((const float4*)emb)[z[n] * 32 + c4];
    ((float4*)x)[n * 32 + c4] = v;
  }
}

// ---------------- attr precompute (sorted order, A-fragment layout) --------
__global__ __launch_bounds__(256)
void k_attr(const int* __restrict__ ei, const float* __restrict__ ew,
            const int* __restrict__ eids,
            const float* __restrict__ means, const float* __restrict__ betas,
            unsigned short* __restrict__ attr_fr, float* __restrict__ Csrt,
            int* __restrict__ srcj) {
  int gid = blockIdx.x * blockDim.x + threadIdx.x;
  int tile = gid >> 9, s = gid & 511;
  int kg = s >> 6, e = s & 63;
  int p = tile * 64 + e;
  int eo = eids[p];
  float d = ew[eo];
  float C = cutoff_f(d);
  float ex = __expf(-d);
  short8 out;
  #pragma unroll
  for (int i = 0; i < 8; ++i) {
    int k = kg * 8 + i;
    float v = 0.0f;
    if (k < RD) {
      float em = ex - means[k];
      v = C * __expf(-betas[k] * em * em);
    }
    out[i] = (short)bf16bits(v);
  }
  *(short8*)(attr_fr + (size_t)gid * 8) = out;
  if (kg == 0) {
    Csrt[p] = C;
    srcj[p] = ei[eo];
  }
}

// ---------------- Pass A: per-edge filter via MFMA ----------------
template <bool TWO>
__global__ __launch_bounds__(256, 2)
void k_filter(const unsigned short* __restrict__ afr_g,
              const float* __restrict__ Csrt,
              const float* __restrict__ w1g, const float* __restrict__ b1g,
              const float* __restrict__ w2g, const float* __restrict__ bFg,
              unsigned short* __restrict__ Wout) {
  __shared__ unsigned short s_u[8192];
  int t = threadIdx.x;
  int wv = t >> 6, lane = t & 63;
  int c = lane & 15, g = lane >> 4;

  short8 B1[2][2];
  #pragma unroll
  for (int ntl = 0; ntl < 2; ++ntl) {
    int col = (2 * wv + ntl) * 16 + c;
    #pragma unroll
    for (int kt = 0; kt < 2; ++kt) {
      short8 v;
      #pragma unroll
      for (int i = 0; i < 8; ++i) {
        int k = 32 * kt + 8 * g + i;
        v[i] = (k < RD) ? (short)bf16bits(w1g[k * HD + col]) : (short)0;
      }
      B1[ntl][kt] = v;
    }
  }
  short8 B2[2][4];
  if (TWO) {
    #pragma unroll
    for (int ntl = 0; ntl < 2; ++ntl) {
      int col = (2 * wv + ntl) * 16 + c;
      #pragma unroll
      for (int kt = 0; kt < 4; ++kt) {
        short8 v;
        #pragma unroll
        for (int i = 0; i < 8; ++i) {
          int k = 32 * kt + 8 * g + i;
          v[i] = (short)bf16bits(w2g[k * HD + col]);
        }
        B2[ntl][kt] = v;
      }
    }
  }
  float b1v[2], bFv[2];
  #pragma unroll
  for (int ntl = 0; ntl < 2; ++ntl) {
    int col = (2 * wv + ntl) * 16 + c;
    b1v[ntl] = TWO ? b1g[col] : 0.0f;
    bFv[ntl] = bFg[col];
  }

  for (int tile = blockIdx.x; tile < NTILES; tile += gridDim.x) {
    const unsigned short* afr = afr_g + (size_t)tile * 4096;
    f32x4 acc[4][2];
    #pragma unroll
    for (int mt = 0; mt < 4; ++mt) {
      acc[mt][0] = (f32x4){0.f, 0.f, 0.f, 0.f};
      acc[mt][1] = (f32x4){0.f, 0.f, 0.f, 0.f};
    }
    #pragma unroll
    for (int kt = 0; kt < 2; ++kt) {
      #pragma unroll
      for (int mt = 0; mt < 4; ++mt) {
        short8 a = *(const short8*)(afr + ((size_t)((4 * kt + g) * 64 + (16 * mt + c))) * 8);
        acc[mt][0] = mfma16(a, B1[0][kt], acc[mt][0]);
        acc[mt][1] = mfma16(a, B1[1][kt], acc[mt][1]);
      }
    }
    if (TWO) {
      #pragma unroll
      for (int mt = 0; mt < 4; ++mt) {
        #pragma unroll
        for (int ntl = 0; ntl < 2; ++ntl) {
          int ch = (2 * wv + ntl) * 16 + c;
          #pragma unroll
          for (int r = 0; r < 4; ++r) {
            int e = 16 * mt + 4 * g + r;
            float v = acc[mt][ntl][r] + b1v[ntl];
            v = silu_f(v);
            s_u[((ch >> 3) * 64 + e) * 8 + (ch & 7)] = bf16bits(v);
          }
        }
      }
      __syncthreads();
      #pragma unroll
      for (int mt = 0; mt < 4; ++mt) {
        acc[mt][0] = (f32x4){0.f, 0.f, 0.f, 0.f};
        acc[mt][1] = (f32x4){0.f, 0.f, 0.f, 0.f};
      }
      #pragma unroll
      for (int kt = 0; kt < 4; ++kt) {
        #pragma unroll
        for (int mt = 0; mt < 4; ++mt) {
          short8 a = *(const short8*)(s_u + ((4 * kt + g) * 64 + (16 * mt + c)) * 8);
          acc[mt][0] = mfma16(a, B2[0][kt], acc[mt][0]);
          acc[mt][1] = mfma16(a, B2[1][kt], acc[mt][1]);
        }
      }
      __syncthreads();
    }
    #pragma unroll
    for (int mt = 0; mt < 4; ++mt) {
      float Cv[4];
      #pragma unroll
      for (int r = 0; r < 4; ++r) Cv[r] = Csrt[tile * 64 + 16 * mt + 4 * g + r];
      #pragma unroll
      for (int ntl = 0; ntl < 2; ++ntl) {
        int ch = (2 * wv + ntl) * 16 + c;
        #pragma unroll
        for (int r = 0; r < 4; ++r) {
          int e = 16 * mt + 4 * g + r;
          float v = (acc[mt][ntl][r] + bFv[ntl]) * Cv[r];
          s_u[e * 128 + ch] = bf16bits(v);
        }
      }
    }
    __syncthreads();
    {
      short8* dst = (short8*)(Wout + (size_t)tile * 8192);
      const short8* srcv = (const short8*)s_u;
      #pragma unroll
      for (int k = 0; k < 4; ++k) dst[t + 256 * k] = srcv[t + 256 * k];
    }
    __syncthreads();
  }
}

// ---------------- Pass B: segment sum ----------------
template <bool INV>
__global__ __launch_bounds__(256)
void k_segsum(const unsigned short* __restrict__ Wst, const float* __restrict__ h,
              const int* __restrict__ rowptr, const int* __restrict__ srcj,
              float* __restrict__ out) {
  int t = threadIdx.x, wv = t >> 6, lane = t & 63;
  int gw = blockIdx.x * 4 + wv, nw = gridDim.x * 4;
  for (int n = gw; n < N_NODES; n += nw) {
    int beg = rowptr[n], end = rowptr[n + 1];
    float a0 = 0.f, a1 = 0.f;
    for (int p = beg; p < end; ++p) {
      int j = srcj[p];
      unsigned int wb = *(const unsigned int*)(Wst + (size_t)p * 128 + 2 * lane);
      float2 hv = *(const float2*)(h + (size_t)j * 128 + 2 * lane);
      a0 += hv.x * bfu_hi(wb << 16);
      a1 += hv.y * bfu_hi(wb & 0xffff0000u);
    }
    float inv = 1.0f;
    if (INV) inv = (end > beg) ? 1.0f / (float)(end - beg) : 0.0f;
    *(float2*)(out + (size_t)n * 128 + 2 * lane) = make_float2(a0 * inv, a1 * inv);
  }
}

// ---------------- MFMA node GEMM, split-bf16 (fp32-grade) ----------------
// out[rows] = [silu](in @ W + bias) [+= out]. K = KT*32 (128 or 256; k>=128 from in2).
// 512 threads = 8 waves; wave w owns output cols 16w..16w+15; block owns 64 rows.
template <int KT, bool HASB, bool SILU, bool ADD>
__global__ __launch_bounds__(512)
void k_nmfma(const float* __restrict__ in1, const float* __restrict__ in2,
             const float* __restrict__ Wg, const float* __restrict__ bias,
             float* __restrict__ out) {
  int t = threadIdx.x;
  int wv = t >> 6, lane = t & 63;
  int c = lane & 15, g = lane >> 4;
  int col = 16 * wv + c;
  int n0 = blockIdx.x * 64;

  short8 Bh[KT], Bl[KT];
  #pragma unroll
  for (int kt = 0; kt < KT; ++kt) {
    short8 h, l;
    #pragma unroll
    for (int i = 0; i < 8; ++i) {
      int k = 32 * kt + 8 * g + i;
      float w = Wg[(size_t)k * HD + col];
      unsigned short hb = bf16bits(w);
      h[i] = (short)hb;
      l[i] = (short)bf16bits(w - bfu_hi((unsigned int)hb << 16));
    }
    Bh[kt] = h; Bl[kt] = l;
  }

  f32x4 acc[4];
  #pragma unroll
  for (int mt = 0; mt < 4; ++mt) acc[mt] = (f32x4){0.f, 0.f, 0.f, 0.f};

  #pragma unroll
  for (int kt = 0; kt < KT; ++kt) {
    const float* in = (KT == 8 && kt >= 4) ? in2 : in1;
    int koff = (kt & 3) * 32 + 8 * g;
    #pragma unroll
    for (int mt = 0; mt < 4; ++mt) {
      int row = n0 + 16 * mt + c;
      int rowc = row < N_NODES ? row : N_NODES - 1;
      short8 ah, al;
      split8(in + (size_t)rowc * HD + koff, ah, al);
      acc[mt] = mfma16(ah, Bh[kt], acc[mt]);
      acc[mt] = mfma16(al, Bh[kt], acc[mt]);
      acc[mt] = mfma16(ah, Bl[kt], acc[mt]);
    }
  }
  __syncthreads();   // all reads done before any in-place store
  float bv = HASB ? bias[col] : 0.0f;
  #pragma unroll
  for (int mt = 0; mt < 4; ++mt) {
    #pragma unroll
    for (int r = 0; r < 4; ++r) {
      int row = n0 + 16 * mt + 4 * g + r;
      if (row < N_NODES) {
        float v = acc[mt][r] + bv;
        if (SILU) v = silu_f(v);
        if (ADD) out[(size_t)row * HD + col] += v;
        else out[(size_t)row * HD + col] = v;
      }
    }
  }
}

// ---------------- fused lin2+silu+lin+residual ----------------
// x[rows] += (silu(in1 @ W1 + b1)) @ W2 + b2, all split-bf16 3-product.
__global__ __launch_bounds__(512)
void k_nmfma2(const float* __restrict__ in1,
              const float* __restrict__ W1, const float* __restrict__ b1,
              const float* __restrict__ W2, const float* __restrict__ b2,
              float* __restrict__ xout) {
  __shared__ unsigned short s_uh[8192];
  __shared__ unsigned short s_ul[8192];
  int t = threadIdx.x;
  int wv = t >> 6, lane = t & 63;
  int c = lane & 15, g = lane >> 4;
  int col = 16 * wv + c;
  int n0 = blockIdx.x * 64;

  short8 B1h[4], B1l[4], B2h[4], B2l[4];
  #pragma unroll
  for (int kt = 0; kt < 4; ++kt) {
    short8 h1, l1, h2, l2;
    #pragma unroll
    for (int i = 0; i < 8; ++i) {
      int k = 32 * kt + 8 * g + i;
      float w = W1[(size_t)k * HD + col];
      unsigned short hb = bf16bits(w);
      h1[i] = (short)hb;
      l1[i] = (short)bf16bits(w - bfu_hi((unsigned int)hb << 16));
      float w2 = W2[(size_t)k * HD + col];
      unsigned short hb2 = bf16bits(w2);
      h2[i] = (short)hb2;
      l2[i] = (short)bf16bits(w2 - bfu_hi((unsigned int)hb2 << 16));
    }
    B1h[kt] = h1; B1l[kt] = l1; B2h[kt] = h2; B2l[kt] = l2;
  }
  float b1v = b1[col], b2v = b2[col];

  f32x4 acc[4];
  #pragma unroll
  for (int mt = 0; mt < 4; ++mt) acc[mt] = (f32x4){0.f, 0.f, 0.f, 0.f};
  #pragma unroll
  for (int kt = 0; kt < 4; ++kt) {
    int koff = kt * 32 + 8 * g;
    #pragma unroll
    for (int mt = 0; mt < 4; ++mt) {
      int row = n0 + 16 * mt + c;
      int rowc = row < N_NODES ? row : N_NODES - 1;
      short8 ah, al;
      split8(in1 + (size_t)rowc * HD + koff, ah, al);
      acc[mt] = mfma16(ah, B1h[kt], acc[mt]);
      acc[mt] = mfma16(al, B1h[kt], acc[mt]);
      acc[mt] = mfma16(ah, B1l[kt], acc[mt]);
    }
  }
  // u = silu(acc + b1), stage hi/lo as A-fragments
  #pragma unroll
  for (int mt = 0; mt < 4; ++mt) {
    #pragma unroll
    for (int r = 0; r < 4; ++r) {
      int e = 16 * mt + 4 * g + r;
      float v = silu_f(acc[mt][r] + b1v);
      unsigned short hb = bf16bits(v);
      unsigned short lb = bf16bits(v - bfu_hi((unsigned int)hb << 16));
      int idx = ((col >> 3) * 64 + e) * 8 + (col & 7);
      s_uh[idx] = hb;
      s_ul[idx] = lb;
    }
  }
  __syncthreads();
  #pragma unroll
  for (int mt = 0; mt < 4; ++mt) acc[mt] = (f32x4){0.f, 0.f, 0.f, 0.f};
  #pragma unroll
  for (int kt = 0; kt < 4; ++kt) {
    #pragma unroll
    for (int mt = 0; mt < 4; ++mt) {
      int idx = ((4 * kt + g) * 64 + (16 * mt + c)) * 8;
      short8 ah = *(const short8*)(s_uh + idx);
      short8 al = *(const short8*)(s_ul + idx);
      acc[mt] = mfma16(ah, B2h[kt], acc[mt]);
      acc[mt] = mfma16(al, B2h[kt], acc[mt]);
      acc[mt] = mfma16(ah, B2l[kt], acc[mt]);
    }
  }
  #pragma unroll
  for (int mt = 0; mt < 4; ++mt) {
    #pragma unroll
    for (int r = 0; r < 4; ++r) {
      int row = n0 + 16 * mt + 4 * g + r;
      if (row < N_NODES) {
        xout[(size_t)row * HD + col] += acc[mt][r] + b2v;
      }
    }
  }
}

extern "C" void kernel_launch(void* const* d_in, const int* in_sizes, int n_in,
                              void* d_out, int out_size, void* d_ws, size_t ws_size,
                              hipStream_t stream) {
  const int* z = (const int*)d_in[0];
  const int* ei = (const int*)d_in[1];
  const float* ew = (const float*)d_in[2];
  const float* emb = (const float*)d_in[3];
  const float* means = (const float*)d_in[4];
  const float* betas = (const float*)d_in[5];
  const float* dp_w = (const float*)d_in[6];
  const float* dp_b = (const float*)d_in[7];
  const float* comb_w = (const float*)d_in[8];
  const float* comb_b = (const float*)d_in[9];
  const float* mlp_w1 = (const float*)d_in[10];
  const float* mlp_b1 = (const float*)d_in[11];
  const float* mlp_w2 = (const float*)d_in[12];
  const float* mlp_b2 = (const float*)d_in[13];
  const float* lin1_w = (const float*)d_in[14];
  const float* lin2_w = (const float*)d_in[15];
  const float* lin2_b = (const float*)d_in[16];
  const float* lin_w = (const float*)d_in[17];
  const float* lin_b = (const float*)d_in[18];
  float* x = (float*)d_out;

  int* rowptr = (int*)d_ws;                         // 20032
  int* deg = rowptr + 20032;                        // 20032
  int* cursor = deg + 20032;                        // 20032
  int* eids = cursor + 20032;                       // E
  int* srcj = eids + N_EDGES;                       // E
  float* Csrt = (float*)(srcj + N_EDGES);           // E
  unsigned short* attr_fr = (unsigned short*)(Csrt + N_EDGES);   // E*64 bf16
  unsigned short* Wst = attr_fr + (size_t)N_EDGES * 64;          // E*128 bf16
  float* hbuf = (float*)(Wst + (size_t)N_EDGES * 128);
  float* aggb = hbuf + (size_t)N_NODES * HD;

  hipMemsetAsync(deg, 0, N_NODES * sizeof(int), stream);
  k_hist<<<(N_EDGES + 255) / 256, 256, 0, stream>>>(ei, deg);
  k_scan<<<1, 1024, 0, stream>>>(deg, rowptr, cursor);
  k_scatter<<<(N_EDGES + 255) / 256, 256, 0, stream>>>(ei, cursor, eids);
  k_attr<<<NTILES * 2, 256, 0, stream>>>(ei, ew, eids, means, betas,
                                         attr_fr, Csrt, srcj);
  k_init<<<(N_NODES * 32 + 255) / 256, 256, 0, stream>>>(z, emb, x);

  // dp block
  k_filter<false><<<1250, 256, 0, stream>>>(attr_fr, Csrt, dp_w, nullptr,
                                            nullptr, dp_b, Wst);
  k_segsum<false><<<1024, 256, 0, stream>>>(Wst, x, rowptr, srcj, aggb);
  k_nmfma<8, true, false, false><<<NROWT, 512, 0, stream>>>(x, aggb, comb_w, comb_b, x);

  for (int l = 0; l < NL; ++l) {
    k_nmfma<4, false, false, false><<<NROWT, 512, 0, stream>>>(
        x, nullptr, lin1_w + (size_t)l * HD * HD, nullptr, hbuf);
    k_filter<true><<<1250, 256, 0, stream>>>(
        attr_fr, Csrt,
        mlp_w1 + (size_t)l * RD * HD, mlp_b1 + (size_t)l * HD,
        mlp_w2 + (size_t)l * HD * HD, mlp_b2 + (size_t)l * HD, Wst);
    k_segsum<true><<<1024, 256, 0, stream>>>(Wst, hbuf, rowptr, srcj, aggb);
    k_nmfma2<<<NROWT, 512, 0, stream>>>(
        aggb, lin2_w + (size_t)l * HD * HD, lin2_b + (size_t)l * HD,
        lin_w + (size_t)l * HD * HD, lin_b + (size_t)l * HD, x);
  }
}

// Round 4
// 942.227 us; speedup vs baseline: 3.8027x; 1.2193x over previous
//
#include <hip/hip_runtime.h>
#include <math.h>

#define N_NODES 20000
#define N_EDGES 320000
#define NTILES  5000   // N_EDGES / 64
#define NROWT   313    // ceil(N_NODES/64)
#define HD 128
#define RD 50
#define NL 6
#define CUTV 5.0f
#define PI_F 3.14159265358979323846f

typedef __attribute__((ext_vector_type(8))) short short8;
typedef __attribute__((ext_vector_type(4))) float f32x4;

__device__ __forceinline__ float cutoff_f(float d) {
  float c = 0.5f * (__cosf(d * (PI_F / CUTV)) + 1.0f);
  return d < CUTV ? c : 0.0f;
}
__device__ __forceinline__ float silu_f(float x) {
  return x / (1.0f + __expf(-x));
}
__device__ __forceinline__ unsigned short bf16bits(float f) {
  union { float f; unsigned int u; } v; v.f = f;
  unsigned int r = v.u + 0x7fffu + ((v.u >> 16) & 1u);
  return (unsigned short)(r >> 16);
}
__device__ __forceinline__ float bfu_hi(unsigned int bits_in_high) {
  union { unsigned int u; float f; } v; v.u = bits_in_high; return v.f;
}
__device__ __forceinline__ f32x4 mfma16(short8 a, short8 b, f32x4 c) {
  return __builtin_amdgcn_mfma_f32_16x16x32_bf16(a, b, c, 0, 0, 0);
}
__device__ __forceinline__ void wave_sync_lds() {
  asm volatile("s_waitcnt lgkmcnt(0)" ::: "memory");
  __builtin_amdgcn_wave_barrier();
}
// split 8 consecutive floats into hi/lo bf16 fragments
__device__ __forceinline__ void split8(const float* __restrict__ p,
                                       short8& h, short8& l) {
  float4 v0 = *(const float4*)p;
  float4 v1 = *(const float4*)(p + 4);
  float vv[8] = {v0.x, v0.y, v0.z, v0.w, v1.x, v1.y, v1.z, v1.w};
  #pragma unroll
  for (int i = 0; i < 8; ++i) {
    unsigned short hb = bf16bits(vv[i]);
    h[i] = (short)hb;
    l[i] = (short)bf16bits(vv[i] - bfu_hi((unsigned int)hb << 16));
  }
}

// ---------------- CSR build ----------------
__global__ void k_hist(const int* __restrict__ ei, int* __restrict__ deg) {
  int e = blockIdx.x * blockDim.x + threadIdx.x;
  if (e < N_EDGES) atomicAdd(&deg[ei[N_EDGES + e]], 1);
}

__global__ void k_scan(const int* __restrict__ deg, int* __restrict__ rowptr,
                       int* __restrict__ cursor) {
  __shared__ int s[1024];
  __shared__ int run;
  int t = threadIdx.x;
  if (t == 0) run = 0;
  __syncthreads();
  for (int base = 0; base < N_NODES; base += 1024) {
    int idx = base + t;
    int v = (idx < N_NODES) ? deg[idx] : 0;
    s[t] = v;
    __syncthreads();
    for (int off = 1; off < 1024; off <<= 1) {
      int add = (t >= off) ? s[t - off] : 0;
      __syncthreads();
      s[t] += add;
      __syncthreads();
    }
    int excl = s[t] - v;
    int r = run;
    if (idx < N_NODES) { rowptr[idx] = r + excl; cursor[idx] = r + excl; }
    __syncthreads();
    if (t == 0) run += s[1023];
    __syncthreads();
  }
  if (t == 0) rowptr[N_NODES] = run;
}

__global__ void k_scatter(const int* __restrict__ ei, int* __restrict__ cursor,
                          int* __restrict__ eids) {
  int e = blockIdx.x * blockDim.x + threadIdx.x;
  if (e < N_EDGES) {
    int i = ei[N_EDGES + e];
    int p = atomicAdd(&cursor[i], 1);
    eids[p] = e;
  }
}

// ---------------- x0 = emb[z] ----------------
__global__ void k_init(const int* __restrict__ z, const float* __restrict__ emb,
                       float* __restrict__ x) {
  int idx = blockIdx.x * blockDim.x + threadIdx.x;
  if (idx < N_NODES * 32) {
    int n = idx >> 5, c4 = idx & 31;
    float4 v = ((const float4*)emb)[z[n] * 32 + c4];
    ((float4*)x)[n * 32 + c4] = v;
  }
}

// ---------------- attr precompute (sorted order, A-fragment layout) --------
__global__ __launch_bounds__(256)
void k_attr(const int* __restrict__ ei, const float* __restrict__ ew,
            const int* __restrict__ eids,
            const float* __restrict__ means, const float* __restrict__ betas,
            unsigned short* __restrict__ attr_fr, float* __restrict__ Csrt,
            int* __restrict__ srcj) {
  int gid = blockIdx.x * blockDim.x + threadIdx.x;
  int tile = gid >> 9, s = gid & 511;
  int kg = s >> 6, e = s & 63;
  int p = tile * 64 + e;
  int eo = eids[p];
  float d = ew[eo];
  float C = cutoff_f(d);
  float ex = __expf(-d);
  short8 out;
  #pragma unroll
  for (int i = 0; i < 8; ++i) {
    int k = kg * 8 + i;
    float v = 0.0f;
    if (k < RD) {
      float em = ex - means[k];
      v = C * __expf(-betas[k] * em * em);
    }
    out[i] = (short)bf16bits(v);
  }
  *(short8*)(attr_fr + (size_t)gid * 8) = out;
  if (kg == 0) {
    Csrt[p] = C;
    srcj[p] = ei[eo];
  }
}

// ---------------- Pass A: per-edge filter via MFMA ----------------
template <bool TWO>
__global__ __launch_bounds__(256, 2)
void k_filter(const unsigned short* __restrict__ afr_g,
              const float* __restrict__ Csrt,
              const float* __restrict__ w1g, const float* __restrict__ b1g,
              const float* __restrict__ w2g, const float* __restrict__ bFg,
              unsigned short* __restrict__ Wout) {
  __shared__ unsigned short s_u[8192];
  int t = threadIdx.x;
  int wv = t >> 6, lane = t & 63;
  int c = lane & 15, g = lane >> 4;

  short8 B1[2][2];
  #pragma unroll
  for (int ntl = 0; ntl < 2; ++ntl) {
    int col = (2 * wv + ntl) * 16 + c;
    #pragma unroll
    for (int kt = 0; kt < 2; ++kt) {
      short8 v;
      #pragma unroll
      for (int i = 0; i < 8; ++i) {
        int k = 32 * kt + 8 * g + i;
        v[i] = (k < RD) ? (short)bf16bits(w1g[k * HD + col]) : (short)0;
      }
      B1[ntl][kt] = v;
    }
  }
  short8 B2[2][4];
  if (TWO) {
    #pragma unroll
    for (int ntl = 0; ntl < 2; ++ntl) {
      int col = (2 * wv + ntl) * 16 + c;
      #pragma unroll
      for (int kt = 0; kt < 4; ++kt) {
        short8 v;
        #pragma unroll
        for (int i = 0; i < 8; ++i) {
          int k = 32 * kt + 8 * g + i;
          v[i] = (short)bf16bits(w2g[k * HD + col]);
        }
        B2[ntl][kt] = v;
      }
    }
  }
  float b1v[2], bFv[2];
  #pragma unroll
  for (int ntl = 0; ntl < 2; ++ntl) {
    int col = (2 * wv + ntl) * 16 + c;
    b1v[ntl] = TWO ? b1g[col] : 0.0f;
    bFv[ntl] = bFg[col];
  }

  for (int tile = blockIdx.x; tile < NTILES; tile += gridDim.x) {
    const unsigned short* afr = afr_g + (size_t)tile * 4096;
    f32x4 acc[4][2];
    #pragma unroll
    for (int mt = 0; mt < 4; ++mt) {
      acc[mt][0] = (f32x4){0.f, 0.f, 0.f, 0.f};
      acc[mt][1] = (f32x4){0.f, 0.f, 0.f, 0.f};
    }
    #pragma unroll
    for (int kt = 0; kt < 2; ++kt) {
      #pragma unroll
      for (int mt = 0; mt < 4; ++mt) {
        short8 a = *(const short8*)(afr + ((size_t)((4 * kt + g) * 64 + (16 * mt + c))) * 8);
        acc[mt][0] = mfma16(a, B1[0][kt], acc[mt][0]);
        acc[mt][1] = mfma16(a, B1[1][kt], acc[mt][1]);
      }
    }
    if (TWO) {
      #pragma unroll
      for (int mt = 0; mt < 4; ++mt) {
        #pragma unroll
        for (int ntl = 0; ntl < 2; ++ntl) {
          int ch = (2 * wv + ntl) * 16 + c;
          #pragma unroll
          for (int r = 0; r < 4; ++r) {
            int e = 16 * mt + 4 * g + r;
            float v = acc[mt][ntl][r] + b1v[ntl];
            v = silu_f(v);
            s_u[((ch >> 3) * 64 + e) * 8 + (ch & 7)] = bf16bits(v);
          }
        }
      }
      __syncthreads();
      #pragma unroll
      for (int mt = 0; mt < 4; ++mt) {
        acc[mt][0] = (f32x4){0.f, 0.f, 0.f, 0.f};
        acc[mt][1] = (f32x4){0.f, 0.f, 0.f, 0.f};
      }
      #pragma unroll
      for (int kt = 0; kt < 4; ++kt) {
        #pragma unroll
        for (int mt = 0; mt < 4; ++mt) {
          short8 a = *(const short8*)(s_u + ((4 * kt + g) * 64 + (16 * mt + c)) * 8);
          acc[mt][0] = mfma16(a, B2[0][kt], acc[mt][0]);
          acc[mt][1] = mfma16(a, B2[1][kt], acc[mt][1]);
        }
      }
      __syncthreads();
    }
    #pragma unroll
    for (int mt = 0; mt < 4; ++mt) {
      float Cv[4];
      #pragma unroll
      for (int r = 0; r < 4; ++r) Cv[r] = Csrt[tile * 64 + 16 * mt + 4 * g + r];
      #pragma unroll
      for (int ntl = 0; ntl < 2; ++ntl) {
        int ch = (2 * wv + ntl) * 16 + c;
        #pragma unroll
        for (int r = 0; r < 4; ++r) {
          int e = 16 * mt + 4 * g + r;
          float v = (acc[mt][ntl][r] + bFv[ntl]) * Cv[r];
          s_u[e * 128 + ch] = bf16bits(v);
        }
      }
    }
    __syncthreads();
    {
      short8* dst = (short8*)(Wout + (size_t)tile * 8192);
      const short8* srcv = (const short8*)s_u;
      #pragma unroll
      for (int k = 0; k < 4; ++k) dst[t + 256 * k] = srcv[t + 256 * k];
    }
    __syncthreads();
  }
}

// ---------------- Pass B: segment sum (wave-per-node, 2 edges in flight) ----
// Wave split into two 32-lane halves; half owns edge parity, lane owns 4 cols.
template <bool INV>
__global__ __launch_bounds__(256)
void k_segsum(const unsigned short* __restrict__ Wst, const float* __restrict__ h,
              const int* __restrict__ rowptr, const int* __restrict__ srcj,
              float* __restrict__ out) {
  int t = threadIdx.x, wv = t >> 6, lane = t & 63;
  int n = blockIdx.x * 4 + wv;
  if (n >= N_NODES) return;
  int half = lane >> 5;      // edge parity
  int q = lane & 31;         // column group: cols 4q..4q+3
  int beg = rowptr[n], end = rowptr[n + 1];
  float a0 = 0.f, a1 = 0.f, a2 = 0.f, a3 = 0.f;
  #pragma unroll 2
  for (int p = beg + half; p < end; p += 2) {
    int j = srcj[p];
    uint2 wb = *(const uint2*)(Wst + (size_t)p * 128 + 4 * q);
    float4 hv = *(const float4*)(h + (size_t)j * 128 + 4 * q);
    a0 += hv.x * bfu_hi(wb.x << 16);
    a1 += hv.y * bfu_hi(wb.x & 0xffff0000u);
    a2 += hv.z * bfu_hi(wb.y << 16);
    a3 += hv.w * bfu_hi(wb.y & 0xffff0000u);
  }
  // combine the two halves
  a0 += __shfl_xor(a0, 32, 64);
  a1 += __shfl_xor(a1, 32, 64);
  a2 += __shfl_xor(a2, 32, 64);
  a3 += __shfl_xor(a3, 32, 64);
  if (half == 0) {
    float inv = 1.0f;
    if (INV) inv = (end > beg) ? 1.0f / (float)(end - beg) : 0.0f;
    float4 r = make_float4(a0 * inv, a1 * inv, a2 * inv, a3 * inv);
    *(float4*)(out + (size_t)n * 128 + 4 * q) = r;
  }
}

// ---------------- MFMA node GEMM, split-bf16 (fp32-grade) ----------------
template <int KT, bool HASB, bool SILU, bool ADD>
__global__ __launch_bounds__(512)
void k_nmfma(const float* __restrict__ in1, const float* __restrict__ in2,
             const float* __restrict__ Wg, const float* __restrict__ bias,
             float* __restrict__ out) {
  int t = threadIdx.x;
  int wv = t >> 6, lane = t & 63;
  int c = lane & 15, g = lane >> 4;
  int col = 16 * wv + c;
  int n0 = blockIdx.x * 64;

  short8 Bh[KT], Bl[KT];
  #pragma unroll
  for (int kt = 0; kt < KT; ++kt) {
    short8 h, l;
    #pragma unroll
    for (int i = 0; i < 8; ++i) {
      int k = 32 * kt + 8 * g + i;
      float w = Wg[(size_t)k * HD + col];
      unsigned short hb = bf16bits(w);
      h[i] = (short)hb;
      l[i] = (short)bf16bits(w - bfu_hi((unsigned int)hb << 16));
    }
    Bh[kt] = h; Bl[kt] = l;
  }

  f32x4 acc[4];
  #pragma unroll
  for (int mt = 0; mt < 4; ++mt) acc[mt] = (f32x4){0.f, 0.f, 0.f, 0.f};

  #pragma unroll
  for (int kt = 0; kt < KT; ++kt) {
    const float* in = (KT == 8 && kt >= 4) ? in2 : in1;
    int koff = (kt & 3) * 32 + 8 * g;
    #pragma unroll
    for (int mt = 0; mt < 4; ++mt) {
      int row = n0 + 16 * mt + c;
      int rowc = row < N_NODES ? row : N_NODES - 1;
      short8 ah, al;
      split8(in + (size_t)rowc * HD + koff, ah, al);
      acc[mt] = mfma16(ah, Bh[kt], acc[mt]);
      acc[mt] = mfma16(al, Bh[kt], acc[mt]);
      acc[mt] = mfma16(ah, Bl[kt], acc[mt]);
    }
  }
  __syncthreads();   // all reads done before any in-place store
  float bv = HASB ? bias[col] : 0.0f;
  #pragma unroll
  for (int mt = 0; mt < 4; ++mt) {
    #pragma unroll
    for (int r = 0; r < 4; ++r) {
      int row = n0 + 16 * mt + 4 * g + r;
      if (row < N_NODES) {
        float v = acc[mt][r] + bv;
        if (SILU) v = silu_f(v);
        if (ADD) out[(size_t)row * HD + col] += v;
        else out[(size_t)row * HD + col] = v;
      }
    }
  }
}

// ---------------- fused lin2+silu+lin+residual ----------------
__global__ __launch_bounds__(512)
void k_nmfma2(const float* __restrict__ in1,
              const float* __restrict__ W1, const float* __restrict__ b1,
              const float* __restrict__ W2, const float* __restrict__ b2,
              float* __restrict__ xout) {
  __shared__ unsigned short s_uh[8192];
  __shared__ unsigned short s_ul[8192];
  int t = threadIdx.x;
  int wv = t >> 6, lane = t & 63;
  int c = lane & 15, g = lane >> 4;
  int col = 16 * wv + c;
  int n0 = blockIdx.x * 64;

  short8 B1h[4], B1l[4], B2h[4], B2l[4];
  #pragma unroll
  for (int kt = 0; kt < 4; ++kt) {
    short8 h1, l1, h2, l2;
    #pragma unroll
    for (int i = 0; i < 8; ++i) {
      int k = 32 * kt + 8 * g + i;
      float w = W1[(size_t)k * HD + col];
      unsigned short hb = bf16bits(w);
      h1[i] = (short)hb;
      l1[i] = (short)bf16bits(w - bfu_hi((unsigned int)hb << 16));
      float w2 = W2[(size_t)k * HD + col];
      unsigned short hb2 = bf16bits(w2);
      h2[i] = (short)hb2;
      l2[i] = (short)bf16bits(w2 - bfu_hi((unsigned int)hb2 << 16));
    }
    B1h[kt] = h1; B1l[kt] = l1; B2h[kt] = h2; B2l[kt] = l2;
  }
  float b1v = b1[col], b2v = b2[col];

  f32x4 acc[4];
  #pragma unroll
  for (int mt = 0; mt < 4; ++mt) acc[mt] = (f32x4){0.f, 0.f, 0.f, 0.f};
  #pragma unroll
  for (int kt = 0; kt < 4; ++kt) {
    int koff = kt * 32 + 8 * g;
    #pragma unroll
    for (int mt = 0; mt < 4; ++mt) {
      int row = n0 + 16 * mt + c;
      int rowc = row < N_NODES ? row : N_NODES - 1;
      short8 ah, al;
      split8(in1 + (size_t)rowc * HD + koff, ah, al);
      acc[mt] = mfma16(ah, B1h[kt], acc[mt]);
      acc[mt] = mfma16(al, B1h[kt], acc[mt]);
      acc[mt] = mfma16(ah, B1l[kt], acc[mt]);
    }
  }
  #pragma unroll
  for (int mt = 0; mt < 4; ++mt) {
    #pragma unroll
    for (int r = 0; r < 4; ++r) {
      int e = 16 * mt + 4 * g + r;
      float v = silu_f(acc[mt][r] + b1v);
      unsigned short hb = bf16bits(v);
      unsigned short lb = bf16bits(v - bfu_hi((unsigned int)hb << 16));
      int idx = ((col >> 3) * 64 + e) * 8 + (col & 7);
      s_uh[idx] = hb;
      s_ul[idx] = lb;
    }
  }
  __syncthreads();
  #pragma unroll
  for (int mt = 0; mt < 4; ++mt) acc[mt] = (f32x4){0.f, 0.f, 0.f, 0.f};
  #pragma unroll
  for (int kt = 0; kt < 4; ++kt) {
    #pragma unroll
    for (int mt = 0; mt < 4; ++mt) {
      int idx = ((4 * kt + g) * 64 + (16 * mt + c)) * 8;
      short8 ah = *(const short8*)(s_uh + idx);
      short8 al = *(const short8*)(s_ul + idx);
      acc[mt] = mfma16(ah, B2h[kt], acc[mt]);
      acc[mt] = mfma16(al, B2h[kt], acc[mt]);
      acc[mt] = mfma16(ah, B2l[kt], acc[mt]);
    }
  }
  #pragma unroll
  for (int mt = 0; mt < 4; ++mt) {
    #pragma unroll
    for (int r = 0; r < 4; ++r) {
      int row = n0 + 16 * mt + 4 * g + r;
      if (row < N_NODES) {
        xout[(size_t)row * HD + col] += acc[mt][r] + b2v;
      }
    }
  }
}

extern "C" void kernel_launch(void* const* d_in, const int* in_sizes, int n_in,
                              void* d_out, int out_size, void* d_ws, size_t ws_size,
                              hipStream_t stream) {
  const int* z = (const int*)d_in[0];
  const int* ei = (const int*)d_in[1];
  const float* ew = (const float*)d_in[2];
  const float* emb = (const float*)d_in[3];
  const float* means = (const float*)d_in[4];
  const float* betas = (const float*)d_in[5];
  const float* dp_w = (const float*)d_in[6];
  const float* dp_b = (const float*)d_in[7];
  const float* comb_w = (const float*)d_in[8];
  const float* comb_b = (const float*)d_in[9];
  const float* mlp_w1 = (const float*)d_in[10];
  const float* mlp_b1 = (const float*)d_in[11];
  const float* mlp_w2 = (const float*)d_in[12];
  const float* mlp_b2 = (const float*)d_in[13];
  const float* lin1_w = (const float*)d_in[14];
  const float* lin2_w = (const float*)d_in[15];
  const float* lin2_b = (const float*)d_in[16];
  const float* lin_w = (const float*)d_in[17];
  const float* lin_b = (const float*)d_in[18];
  float* x = (float*)d_out;

  int* rowptr = (int*)d_ws;                         // 20032
  int* deg = rowptr + 20032;                        // 20032
  int* cursor = deg + 20032;                        // 20032
  int* eids = cursor + 20032;                       // E
  int* srcj = eids + N_EDGES;                       // E
  float* Csrt = (float*)(srcj + N_EDGES);           // E
  unsigned short* attr_fr = (unsigned short*)(Csrt + N_EDGES);   // E*64 bf16
  unsigned short* Wst = attr_fr + (size_t)N_EDGES * 64;          // E*128 bf16
  float* hbuf = (float*)(Wst + (size_t)N_EDGES * 128);
  float* aggb = hbuf + (size_t)N_NODES * HD;

  hipMemsetAsync(deg, 0, N_NODES * sizeof(int), stream);
  k_hist<<<(N_EDGES + 255) / 256, 256, 0, stream>>>(ei, deg);
  k_scan<<<1, 1024, 0, stream>>>(deg, rowptr, cursor);
  k_scatter<<<(N_EDGES + 255) / 256, 256, 0, stream>>>(ei, cursor, eids);
  k_attr<<<NTILES * 2, 256, 0, stream>>>(ei, ew, eids, means, betas,
                                         attr_fr, Csrt, srcj);
  k_init<<<(N_NODES * 32 + 255) / 256, 256, 0, stream>>>(z, emb, x);

  // dp block
  k_filter<false><<<1250, 256, 0, stream>>>(attr_fr, Csrt, dp_w, nullptr,
                                            nullptr, dp_b, Wst);
  k_segsum<false><<<5000, 256, 0, stream>>>(Wst, x, rowptr, srcj, aggb);
  k_nmfma<8, true, false, false><<<NROWT, 512, 0, stream>>>(x, aggb, comb_w, comb_b, x);

  for (int l = 0; l < NL; ++l) {
    k_nmfma<4, false, false, false><<<NROWT, 512, 0, stream>>>(
        x, nullptr, lin1_w + (size_t)l * HD * HD, nullptr, hbuf);
    k_filter<true><<<1250, 256, 0, stream>>>(
        attr_fr, Csrt,
        mlp_w1 + (size_t)l * RD * HD, mlp_b1 + (size_t)l * HD,
        mlp_w2 + (size_t)l * HD * HD, mlp_b2 + (size_t)l * HD, Wst);
    k_segsum<true><<<5000, 256, 0, stream>>>(Wst, hbuf, rowptr, srcj, aggb);
    k_nmfma2<<<NROWT, 512, 0, stream>>>(
        aggb, lin2_w + (size_t)l * HD * HD, lin2_b + (size_t)l * HD,
        lin_w + (size_t)l * HD * HD, lin_b + (size_t)l * HD, x);
  }
}